// Round 1
// baseline (780.493 us; speedup 1.0000x reference)
//
#include <hip/hip_runtime.h>

typedef __bf16 bf16;
typedef __bf16 bf16x8 __attribute__((ext_vector_type(8)));
typedef __bf16 bf16x4 __attribute__((ext_vector_type(4)));
typedef float  f32x4  __attribute__((ext_vector_type(4)));

#define MFMA16 __builtin_amdgcn_mfma_f32_16x16x32_bf16

static constexpr int   BSZ   = 4;
static constexpr int   SEQL  = 2048;
static constexpr int   DM    = 1024;
static constexpr int   NHEAD = 16;
static constexpr int   DHEAD = 64;
static constexpr float NEGV  = -1e10f;
static constexpr float SCL   = 0.125f;   // 1/sqrt(64)

// ---------------------------------------------------------------------------
// Mask dtype detection: classify first 4096 u32 words.
// flag: 0=int32{0,1}, 1=byte{0,1}, 2=float32{0,1.0f}, 3=bf16{0,0x3F80}
// Random 0/1 content makes each class uniquely identifiable (see analysis).
__global__ void detect_mask(const unsigned int* __restrict__ m, int* __restrict__ flag) {
    __shared__ int ok[4];
    if (threadIdx.x < 4) ok[threadIdx.x] = 1;
    __syncthreads();
    for (int i = 0; i < 16; ++i) {
        unsigned int w = m[threadIdx.x * 16 + i];
        if (!(w == 0u || w == 1u)) ok[0] = 0;
        if (w & 0xFEFEFEFEu) ok[1] = 0;
        if (!(w == 0u || w == 0x3F800000u)) ok[2] = 0;
        unsigned lo = w & 0xFFFFu, hi = w >> 16;
        if (!((lo == 0u || lo == 0x3F80u) && (hi == 0u || hi == 0x3F80u))) ok[3] = 0;
    }
    __syncthreads();
    if (threadIdx.x == 0)
        *flag = ok[0] ? 0 : (ok[1] ? 1 : (ok[2] ? 2 : 3));
}

__device__ __forceinline__ bool mask_at(const void* m, int fl, long idx) {
    if (fl == 0) return ((const int*)m)[idx] != 0;
    if (fl == 1) return ((const unsigned char*)m)[idx] != 0;
    if (fl == 2) return ((const float*)m)[idx] != 0.0f;
    return ((const unsigned short*)m)[idx] != 0;
}

// ---------------------------------------------------------------------------
// LayerNorm: one block per row of 1024. fp32 compute, bf16 out.
__global__ __launch_bounds__(256) void ln_kernel(
    const float* __restrict__ x, const float* __restrict__ g,
    const float* __restrict__ bta, bf16* __restrict__ y)
{
    const int row = blockIdx.x, t = threadIdx.x;
    const float4 v = ((const float4*)(x + (size_t)row * DM))[t];
    float s  = v.x + v.y + v.z + v.w;
    float ss = v.x * v.x + v.y * v.y + v.z * v.z + v.w * v.w;
    for (int m = 32; m >= 1; m >>= 1) { s += __shfl_xor(s, m); ss += __shfl_xor(ss, m); }
    __shared__ float red[8];
    const int w = t >> 6, L = t & 63;
    if (L == 0) { red[w] = s; red[4 + w] = ss; }
    __syncthreads();
    s  = red[0] + red[1] + red[2] + red[3];
    ss = red[4] + red[5] + red[6] + red[7];
    const float mu = s * (1.0f / DM);
    const float var = ss * (1.0f / DM) - mu * mu;
    const float r = rsqrtf(var + 1e-5f);
    const float4 gv = ((const float4*)g)[t];
    const float4 bv = ((const float4*)bta)[t];
    bf16x4 o;
    o[0] = (bf16)((v.x - mu) * r * gv.x + bv.x);
    o[1] = (bf16)((v.y - mu) * r * gv.y + bv.y);
    o[2] = (bf16)((v.z - mu) * r * gv.z + bv.z);
    o[3] = (bf16)((v.w - mu) * r * gv.w + bv.w);
    ((bf16x4*)(y + (size_t)row * DM))[t] = o;
}

// ---------------------------------------------------------------------------
// Transpose+convert the 4 weight matrices (1024x1024 f32, K x N) into bf16 N x K.
__global__ void cvt_w(const float* __restrict__ Wq, const float* __restrict__ Wk,
                      const float* __restrict__ Wv, const float* __restrict__ Wo,
                      bf16* __restrict__ Wt)
{
    __shared__ float tile[32][33];
    const int z = blockIdx.z;
    const float* src = (z == 0) ? Wq : (z == 1) ? Wk : (z == 2) ? Wv : Wo;
    bf16* dst = Wt + (size_t)z * DM * DM;
    const int tx = threadIdx.x, ty = threadIdx.y;
    const int nIn = blockIdx.x * 32 + tx;
    const int kIn = blockIdx.y * 32;
    for (int i = 0; i < 32; i += 8)
        tile[ty + i][tx] = src[(size_t)(kIn + ty + i) * DM + nIn];
    __syncthreads();
    const int nOut = blockIdx.x * 32;
    const int kOut = blockIdx.y * 32 + tx;
    for (int i = 0; i < 32; i += 8)
        dst[(size_t)(nOut + ty + i) * DM + kOut] = (bf16)tile[tx][ty + i];
}

// ---------------------------------------------------------------------------
// 64x64 MFMA GEMM tile: A (MxK bf16 rm), Bt (NxK bf16 rm), K=1024, BK=32.
// 4 waves in 2x2; each wave 32x32 via 2x2 mfma_f32_16x16x32_bf16.
__device__ __forceinline__ void gemm_tile(
    const bf16* __restrict__ A, const bf16* __restrict__ Bt,
    int m0, int n0, f32x4 acc[2][2], bf16* Asm, bf16* Bsm, int t)
{
    const int L = t & 63, w = t >> 6;
    const int wm = w & 1, wn = w >> 1;
    const int lr = L & 15, lq = L >> 4;
    const int r = t >> 2, c0 = (t & 3) * 8;
    for (int kk = 0; kk < DM; kk += 32) {
        __syncthreads();
        *(bf16x8*)(Asm + r * 40 + c0) = *(const bf16x8*)(A + (size_t)(m0 + r) * DM + kk + c0);
        *(bf16x8*)(Bsm + r * 40 + c0) = *(const bf16x8*)(Bt + (size_t)(n0 + r) * DM + kk + c0);
        __syncthreads();
        bf16x8 a0 = *(const bf16x8*)(Asm + (wm * 32 + lr) * 40 + lq * 8);
        bf16x8 a1 = *(const bf16x8*)(Asm + (wm * 32 + 16 + lr) * 40 + lq * 8);
        bf16x8 b0 = *(const bf16x8*)(Bsm + (wn * 32 + lr) * 40 + lq * 8);
        bf16x8 b1 = *(const bf16x8*)(Bsm + (wn * 32 + 16 + lr) * 40 + lq * 8);
        acc[0][0] = MFMA16(a0, b0, acc[0][0], 0, 0, 0);
        acc[0][1] = MFMA16(a0, b1, acc[0][1], 0, 0, 0);
        acc[1][0] = MFMA16(a1, b0, acc[1][0], 0, 0, 0);
        acc[1][1] = MFMA16(a1, b1, acc[1][1], 0, 0, 0);
    }
}

// QKV projection: z selects Wq/Wk/Wv; output written in (b,h,s,d) bf16.
__global__ __launch_bounds__(256) void qkv_gemm(
    const bf16* __restrict__ qn, const bf16* __restrict__ Wt,
    bf16* __restrict__ Qb, bf16* __restrict__ Kb, bf16* __restrict__ Vb)
{
    __shared__ __align__(16) bf16 Asm[64 * 40];
    __shared__ __align__(16) bf16 Bsm[64 * 40];
    const int m0 = blockIdx.x * 64, n0 = blockIdx.y * 64, z = blockIdx.z;
    const bf16* Bt = Wt + (size_t)z * DM * DM;
    f32x4 acc[2][2] = {};
    gemm_tile(qn, Bt, m0, n0, acc, Asm, Bsm, threadIdx.x);
    bf16* dst = (z == 0) ? Qb : (z == 1) ? Kb : Vb;
    const int t = threadIdx.x, L = t & 63, w = t >> 6;
    const int wm = w & 1, wn = w >> 1, lr = L & 15, lq = L >> 4;
    for (int i = 0; i < 2; ++i)
        for (int j = 0; j < 2; ++j)
            for (int r = 0; r < 4; ++r) {
                int m = m0 + wm * 32 + i * 16 + lq * 4 + r;   // b*2048+s
                int n = n0 + wn * 32 + j * 16 + lr;           // h*64+d
                int b = m >> 11, s = m & 2047, h = n >> 6, d = n & 63;
                dst[(((size_t)b * NHEAD + h) * SEQL + s) * DHEAD + d] = (bf16)acc[i][j][r];
            }
}

// Output projection + residual: out = vec @ Wo + qn (fp32 out).
__global__ __launch_bounds__(256) void out_gemm(
    const bf16* __restrict__ vec, const bf16* __restrict__ Wot,
    const bf16* __restrict__ qnb, float* __restrict__ out)
{
    __shared__ __align__(16) bf16 Asm[64 * 40];
    __shared__ __align__(16) bf16 Bsm[64 * 40];
    const int m0 = blockIdx.x * 64, n0 = blockIdx.y * 64;
    f32x4 acc[2][2] = {};
    gemm_tile(vec, Wot, m0, n0, acc, Asm, Bsm, threadIdx.x);
    const int t = threadIdx.x, L = t & 63, w = t >> 6;
    const int wm = w & 1, wn = w >> 1, lr = L & 15, lq = L >> 4;
    for (int i = 0; i < 2; ++i)
        for (int j = 0; j < 2; ++j)
            for (int r = 0; r < 4; ++r) {
                int m = m0 + wm * 32 + i * 16 + lq * 4 + r;
                int n = n0 + wn * 32 + j * 16 + lr;
                size_t idx = (size_t)m * DM + n;
                out[idx] = acc[i][j][r] + (float)qnb[idx];
            }
}

// ---------------------------------------------------------------------------
// Flash attention: grid (32 q-blocks, 64 bh). 4 waves; wave = 16 q-rows.
// KV tiles of 64. QK^T and PV via MFMA; online softmax via LDS round-trip.
__global__ __launch_bounds__(256) void flash_attn(
    const bf16* __restrict__ Qb, const bf16* __restrict__ Kb, const bf16* __restrict__ Vb,
    const void* __restrict__ mask, const int* __restrict__ flagp,
    bf16* __restrict__ vec)
{
    __shared__ __align__(16) bf16 Ksm[64 * 72];     // [key][d]  (native B^T for QK^T)
    __shared__ __align__(16) bf16 Vtsm[64 * 72];    // [d][key]  (B^T for PV)
    __shared__ __align__(16) float Ssm[4][16 * 68]; // per-wave scores 16x64
    __shared__ __align__(16) bf16 Psm[4][16 * 72];  // per-wave P bf16 16x64
    __shared__ float msm[4][16], lsm[4][16], alphm[4][16];

    const int t = threadIdx.x, w = t >> 6, L = t & 63;
    const int lr = L & 15, lq = L >> 4;
    const int bh = blockIdx.y;
    const int b = bh >> 4, h = bh & 15;
    const int q0 = blockIdx.x * 64 + w * 16;        // this wave's first q row
    const int fl = *flagp;

    const bf16* Qh = Qb + (size_t)bh * SEQL * DHEAD;
    const bf16* Kh = Kb + (size_t)bh * SEQL * DHEAD;
    const bf16* Vh = Vb + (size_t)bh * SEQL * DHEAD;

    // Q fragments (A-layout), resident for the whole pass
    bf16x8 qf[2];
    qf[0] = *(const bf16x8*)(Qh + (size_t)(q0 + lr) * DHEAD + lq * 8);
    qf[1] = *(const bf16x8*)(Qh + (size_t)(q0 + lr) * DHEAD + 32 + lq * 8);

    f32x4 o[4] = {};
    if (L < 16) { msm[w][L] = -1e30f; lsm[w][L] = 0.0f; }

    for (int kt = 0; kt < SEQL / 64; ++kt) {
        const int kb = kt * 64;
        __syncthreads();   // protect previous iteration's LDS reads
        {   // stage K tile (as-is) and V tile (transposed)
            const int r = t >> 2, c0 = (t & 3) * 16;
            const bf16* ksrc = Kh + (size_t)(kb + r) * DHEAD + c0;
            *(bf16x8*)(Ksm + r * 72 + c0)     = *(const bf16x8*)(ksrc);
            *(bf16x8*)(Ksm + r * 72 + c0 + 8) = *(const bf16x8*)(ksrc + 8);
            const bf16* vsrc = Vh + (size_t)(kb + r) * DHEAD + c0;
            bf16x8 v0 = *(const bf16x8*)(vsrc);
            bf16x8 v1 = *(const bf16x8*)(vsrc + 8);
            #pragma unroll
            for (int i = 0; i < 8; ++i) {
                Vtsm[(c0 + i) * 72 + r]     = v0[i];
                Vtsm[(c0 + 8 + i) * 72 + r] = v1[i];
            }
        }
        __syncthreads();
        // S = Q K^T  (16 x 64 per wave)
        f32x4 s[4] = {};
        #pragma unroll
        for (int ks = 0; ks < 2; ++ks) {
            bf16x8 a = qf[ks];
            #pragma unroll
            for (int jj = 0; jj < 4; ++jj) {
                bf16x8 bf = *(const bf16x8*)(Ksm + (jj * 16 + lr) * 72 + ks * 32 + lq * 8);
                s[jj] = MFMA16(a, bf, s[jj], 0, 0, 0);
            }
        }
        // scale + mask + spill S to LDS (C-layout -> row-major)
        #pragma unroll
        for (int jj = 0; jj < 4; ++jj)
            #pragma unroll
            for (int r = 0; r < 4; ++r) {
                int row = lq * 4 + r;
                int iq = q0 + row;
                int jk = kb + jj * 16 + lr;
                float val = s[jj][r] * SCL;
                if (mask_at(mask, fl, (long)iq * SEQL + jk)) val = NEGV;
                Ssm[w][row * 68 + jj * 16 + lr] = val;
            }
        __syncthreads();
        // online softmax: lane -> (row = L>>2, 16-col segment = L&3)
        {
            const int row = L >> 2, seg = L & 3;
            const float* Sr = &Ssm[w][row * 68 + seg * 16];
            float mx = -1e30f;
            #pragma unroll
            for (int i = 0; i < 16; ++i) mx = fmaxf(mx, Sr[i]);
            mx = fmaxf(mx, __shfl_xor(mx, 1));
            mx = fmaxf(mx, __shfl_xor(mx, 2));
            const float m_old = msm[w][row];
            const float m_new = fmaxf(m_old, mx);
            const float alpha = __expf(m_old - m_new);
            float lsum = 0.0f;
            bf16* Pr = &Psm[w][row * 72 + seg * 16];
            #pragma unroll
            for (int i = 0; i < 16; ++i) {
                float p = __expf(Sr[i] - m_new);
                lsum += p;
                Pr[i] = (bf16)p;
            }
            lsum += __shfl_xor(lsum, 1);
            lsum += __shfl_xor(lsum, 2);
            if (seg == 0) {
                msm[w][row] = m_new;
                lsm[w][row] = lsm[w][row] * alpha + lsum;
                alphm[w][row] = alpha;
            }
        }
        __syncthreads();
        // rescale O and accumulate P @ V
        #pragma unroll
        for (int jj = 0; jj < 4; ++jj)
            #pragma unroll
            for (int r = 0; r < 4; ++r) o[jj][r] *= alphm[w][lq * 4 + r];
        #pragma unroll
        for (int ks = 0; ks < 2; ++ks) {
            bf16x8 ap = *(const bf16x8*)(&Psm[w][lr * 72 + ks * 32 + lq * 8]);
            #pragma unroll
            for (int jj = 0; jj < 4; ++jj) {
                bf16x8 bv = *(const bf16x8*)(Vtsm + (jj * 16 + lr) * 72 + ks * 32 + lq * 8);
                o[jj] = MFMA16(ap, bv, o[jj], 0, 0, 0);
            }
        }
    }
    __syncthreads();
    // epilogue: divide by l, write vec in (b, s, h*64+d) so out_gemm reads rows
    #pragma unroll
    for (int jj = 0; jj < 4; ++jj)
        #pragma unroll
        for (int r = 0; r < 4; ++r) {
            int row = lq * 4 + r;
            float lv = lsm[w][row];
            int srow = q0 + row;
            int d = jj * 16 + lr;
            vec[((size_t)b * SEQL + srow) * DM + h * DHEAD + d] = (bf16)(o[jj][r] / lv);
        }
}

// ---------------------------------------------------------------------------
extern "C" void kernel_launch(void* const* d_in, const int* in_sizes, int n_in,
                              void* d_out, int out_size, void* d_ws, size_t ws_size,
                              hipStream_t stream)
{
    const float* qin   = (const float*)d_in[0];
    const void*  mask  = d_in[1];
    const float* Wq    = (const float*)d_in[2];
    const float* Wk    = (const float*)d_in[3];
    const float* Wv    = (const float*)d_in[4];
    const float* Wo    = (const float*)d_in[5];
    const float* gamma = (const float*)d_in[6];
    const float* beta  = (const float*)d_in[7];
    float* out = (float*)d_out;

    char* w = (char*)d_ws;
    int*  flag = (int*)w;
    bf16* qnb  = (bf16*)(w + 256);                 // 8192x1024 bf16  (16 MB)
    bf16* Wt   = qnb + (size_t)8192 * 1024;        // 4x 1024x1024 bf16 (8 MB)
    bf16* Qb   = Wt + (size_t)4 * 1024 * 1024;     // (b,h,s,d) bf16 (16 MB)
    bf16* Kb   = Qb + (size_t)8192 * 1024;
    bf16* Vb   = Kb + (size_t)8192 * 1024;
    bf16* vec  = Vb + (size_t)8192 * 1024;         // (b,s,h*d) bf16 (16 MB)

    detect_mask<<<1, 256, 0, stream>>>((const unsigned int*)mask, flag);
    ln_kernel<<<8192, 256, 0, stream>>>(qin, gamma, beta, qnb);
    cvt_w<<<dim3(32, 32, 4), dim3(32, 8), 0, stream>>>(Wq, Wk, Wv, Wo, Wt);
    qkv_gemm<<<dim3(128, 16, 3), 256, 0, stream>>>(qnb, Wt, Qb, Kb, Vb);
    flash_attn<<<dim3(32, 64), 256, 0, stream>>>(Qb, Kb, Vb, mask, flag, vec);
    out_gemm<<<dim3(128, 16), 256, 0, stream>>>(vec, Wt + (size_t)3 * 1024 * 1024, qnb, out);
}

// Round 3
// 472.708 us; speedup vs baseline: 1.6511x; 1.6511x over previous
//
#include <hip/hip_runtime.h>

typedef __bf16 bf16;
typedef __bf16 bf16x8 __attribute__((ext_vector_type(8)));
typedef __bf16 bf16x4 __attribute__((ext_vector_type(4)));
typedef float  f32x4  __attribute__((ext_vector_type(4)));

#define MFMA16 __builtin_amdgcn_mfma_f32_16x16x32_bf16

static constexpr int   BSZ   = 4;
static constexpr int   SEQL  = 2048;
static constexpr int   DM    = 1024;
static constexpr int   NHEAD = 16;
static constexpr int   DHEAD = 64;
static constexpr float NEGV  = -1e10f;
static constexpr float SCL   = 0.125f;   // 1/sqrt(64)

// async global->LDS, 16B per lane; LDS dest = wave-uniform base + lane*16
__device__ __forceinline__ void glds16(bf16* lds, const bf16* g) {
    __builtin_amdgcn_global_load_lds(
        (const __attribute__((address_space(1))) unsigned int*)g,
        (__attribute__((address_space(3))) unsigned int*)lds, 16, 0, 0);
}

// ---------------------------------------------------------------------------
// Mask dtype detection: flag 0=int32{0,1}, 1=byte, 2=float32, 3=bf16
__global__ void detect_mask(const unsigned int* __restrict__ m, int* __restrict__ flag) {
    __shared__ int ok[4];
    if (threadIdx.x < 4) ok[threadIdx.x] = 1;
    __syncthreads();
    for (int i = 0; i < 16; ++i) {
        unsigned int w = m[threadIdx.x * 16 + i];
        if (!(w == 0u || w == 1u)) ok[0] = 0;
        if (w & 0xFEFEFEFEu) ok[1] = 0;
        if (!(w == 0u || w == 0x3F800000u)) ok[2] = 0;
        unsigned lo = w & 0xFFFFu, hi = w >> 16;
        if (!((lo == 0u || lo == 0x3F80u) && (hi == 0u || hi == 0x3F80u))) ok[3] = 0;
    }
    __syncthreads();
    if (threadIdx.x == 0)
        *flag = ok[0] ? 0 : (ok[1] ? 1 : (ok[2] ? 2 : 3));
}

__device__ __forceinline__ bool mask_at(const void* m, int fl, long idx) {
    if (fl == 0) return ((const int*)m)[idx] != 0;
    if (fl == 1) return ((const unsigned char*)m)[idx] != 0;
    if (fl == 2) return ((const float*)m)[idx] != 0.0f;
    return ((const unsigned short*)m)[idx] != 0;
}

// mask -> additive bf16 bias matrix (0 or -1e10), coalesced
__global__ __launch_bounds__(256) void prep_bias(const void* __restrict__ mask,
                                                 const int* __restrict__ flagp,
                                                 bf16* __restrict__ bias) {
    const int fl = *flagp;
    const size_t base = (size_t)blockIdx.x * 2048 + threadIdx.x;
    #pragma unroll
    for (int k = 0; k < 8; ++k) {
        size_t i = base + (size_t)k * 256;
        bias[i] = mask_at(mask, fl, (long)i) ? (bf16)NEGV : (bf16)0.0f;
    }
}

// ---------------------------------------------------------------------------
// LayerNorm: one block per row of 1024. fp32 compute, bf16 out.
__global__ __launch_bounds__(256) void ln_kernel(
    const float* __restrict__ x, const float* __restrict__ g,
    const float* __restrict__ bta, bf16* __restrict__ y)
{
    const int row = blockIdx.x, t = threadIdx.x;
    const float4 v = ((const float4*)(x + (size_t)row * DM))[t];
    float s  = v.x + v.y + v.z + v.w;
    float ss = v.x * v.x + v.y * v.y + v.z * v.z + v.w * v.w;
    for (int m = 32; m >= 1; m >>= 1) { s += __shfl_xor(s, m); ss += __shfl_xor(ss, m); }
    __shared__ float red[8];
    const int w = t >> 6, L = t & 63;
    if (L == 0) { red[w] = s; red[4 + w] = ss; }
    __syncthreads();
    s  = red[0] + red[1] + red[2] + red[3];
    ss = red[4] + red[5] + red[6] + red[7];
    const float mu = s * (1.0f / DM);
    const float var = ss * (1.0f / DM) - mu * mu;
    const float r = rsqrtf(var + 1e-5f);
    const float4 gv = ((const float4*)g)[t];
    const float4 bv = ((const float4*)bta)[t];
    bf16x4 o;
    o[0] = (bf16)((v.x - mu) * r * gv.x + bv.x);
    o[1] = (bf16)((v.y - mu) * r * gv.y + bv.y);
    o[2] = (bf16)((v.z - mu) * r * gv.z + bv.z);
    o[3] = (bf16)((v.w - mu) * r * gv.w + bv.w);
    ((bf16x4*)(y + (size_t)row * DM))[t] = o;
}

// ---------------------------------------------------------------------------
// Transpose+convert 4 weight matrices (1024x1024 f32, KxN) into bf16 NxK.
__global__ void cvt_w(const float* __restrict__ Wq, const float* __restrict__ Wk,
                      const float* __restrict__ Wv, const float* __restrict__ Wo,
                      bf16* __restrict__ Wt)
{
    __shared__ float tile[32][33];
    const int z = blockIdx.z;
    const float* src = (z == 0) ? Wq : (z == 1) ? Wk : (z == 2) ? Wv : Wo;
    bf16* dst = Wt + (size_t)z * DM * DM;
    const int tx = threadIdx.x, ty = threadIdx.y;
    const int nIn = blockIdx.x * 32 + tx;
    const int kIn = blockIdx.y * 32;
    for (int i = 0; i < 32; i += 8)
        tile[ty + i][tx] = src[(size_t)(kIn + ty + i) * DM + nIn];
    __syncthreads();
    const int nOut = blockIdx.x * 32;
    const int kOut = blockIdx.y * 32 + tx;
    for (int i = 0; i < 32; i += 8)
        dst[(size_t)(nOut + ty + i) * DM + kOut] = (bf16)tile[tx][ty + i];
}

// ---------------------------------------------------------------------------
// m97-style 128x128 GEMM core: A (MxK rm), Bt (NxK rm), BK=32, global_load_lds.
// 4 waves in 2x2, each 64x64 via 4x4 mfma_f32_16x16x32_bf16.
// swapped=true computes D^T (operands exchanged) for free V transpose.
__device__ __forceinline__ void gemm128_core(
    const bf16* __restrict__ A, const bf16* __restrict__ Bt,
    int m0, int n0, bool swapped, f32x4 acc[4][4], bf16* Asm, bf16* Bsm)
{
    const int t = threadIdx.x, w = t >> 6, L = t & 63;
    const int lr = L & 15, lq = L >> 4;
    const int wm = w & 1, wn = w >> 1;
    const int srow = L >> 2, scol = (L & 3) * 8;     // lane -> (row, 8-elem slice)
    const bf16* Ab = A  + (size_t)(m0 + w * 32 + srow) * DM + scol;
    const bf16* Bb = Bt + (size_t)(n0 + w * 32 + srow) * DM + scol;
    bf16* AsmW = Asm + (w * 32) * 32;                // wave-uniform LDS bases
    bf16* BsmW = Bsm + (w * 32) * 32;
    for (int kk = 0; kk < DM; kk += 32) {
        __syncthreads();
        glds16(AsmW,           Ab + kk);
        glds16(AsmW + 16 * 32, Ab + (size_t)16 * DM + kk);
        glds16(BsmW,           Bb + kk);
        glds16(BsmW + 16 * 32, Bb + (size_t)16 * DM + kk);
        __syncthreads();
        bf16x8 af[4], bf_[4];
        #pragma unroll
        for (int i = 0; i < 4; ++i)
            af[i] = *(const bf16x8*)(Asm + (wm * 64 + i * 16 + lr) * 32 + lq * 8);
        #pragma unroll
        for (int j = 0; j < 4; ++j)
            bf_[j] = *(const bf16x8*)(Bsm + (wn * 64 + j * 16 + lr) * 32 + lq * 8);
        if (!swapped) {
            #pragma unroll
            for (int i = 0; i < 4; ++i)
                #pragma unroll
                for (int j = 0; j < 4; ++j)
                    acc[i][j] = MFMA16(af[i], bf_[j], acc[i][j], 0, 0, 0);
        } else {
            #pragma unroll
            for (int i = 0; i < 4; ++i)
                #pragma unroll
                for (int j = 0; j < 4; ++j)
                    acc[i][j] = MFMA16(bf_[j], af[i], acc[i][j], 0, 0, 0);
        }
    }
}

// QKV projection. z=0,1 -> Q,K in (b,h,s,d); z=2 -> V^T in (b,h,d,s).
__global__ __launch_bounds__(256) void qkv128(
    const bf16* __restrict__ qn, const bf16* __restrict__ Wt,
    bf16* __restrict__ Qb, bf16* __restrict__ Kb, bf16* __restrict__ Vtb)
{
    __shared__ __align__(16) bf16 Asm[128 * 32];
    __shared__ __align__(16) bf16 Bsm[128 * 32];
    const int z = blockIdx.z;
    const int m0 = blockIdx.x * 128, n0 = blockIdx.y * 128;
    f32x4 acc[4][4] = {};
    gemm128_core(qn, Wt + (size_t)z * DM * DM, m0, n0, z == 2, acc, Asm, Bsm);
    const int t = threadIdx.x, L = t & 63, w = t >> 6;
    const int wm = w & 1, wn = w >> 1, lr = L & 15, lq = L >> 4;
    if (z < 2) {
        bf16* dst = z ? Kb : Qb;
        #pragma unroll
        for (int i = 0; i < 4; ++i)
            #pragma unroll
            for (int j = 0; j < 4; ++j)
                #pragma unroll
                for (int r = 0; r < 4; ++r) {
                    int m = m0 + wm * 64 + i * 16 + lq * 4 + r;   // b*2048+s
                    int n = n0 + wn * 64 + j * 16 + lr;           // h*64+d
                    int b = m >> 11, s = m & 2047, h = n >> 6, d = n & 63;
                    dst[(((size_t)b * NHEAD + h) * SEQL + s) * DHEAD + d] = (bf16)acc[i][j][r];
                }
    } else {
        #pragma unroll
        for (int i = 0; i < 4; ++i)
            #pragma unroll
            for (int j = 0; j < 4; ++j)
                #pragma unroll
                for (int r = 0; r < 4; ++r) {
                    int dg = n0 + wn * 64 + j * 16 + lq * 4 + r;  // h*64+d (D rows)
                    int sg = m0 + wm * 64 + i * 16 + lr;          // b*2048+s (D cols)
                    int h = dg >> 6, d = dg & 63, b = sg >> 11, s = sg & 2047;
                    Vtb[(((size_t)b * NHEAD + h) * DHEAD + d) * SEQL + s] = (bf16)acc[i][j][r];
                }
    }
}

// Output projection + residual (fp32 out).
__global__ __launch_bounds__(256) void out128(
    const bf16* __restrict__ vec, const bf16* __restrict__ Wot,
    const bf16* __restrict__ qnb, float* __restrict__ out)
{
    __shared__ __align__(16) bf16 Asm[128 * 32];
    __shared__ __align__(16) bf16 Bsm[128 * 32];
    const int m0 = blockIdx.x * 128, n0 = blockIdx.y * 128;
    f32x4 acc[4][4] = {};
    gemm128_core(vec, Wot, m0, n0, false, acc, Asm, Bsm);
    const int t = threadIdx.x, L = t & 63, w = t >> 6;
    const int wm = w & 1, wn = w >> 1, lr = L & 15, lq = L >> 4;
    #pragma unroll
    for (int i = 0; i < 4; ++i)
        #pragma unroll
        for (int j = 0; j < 4; ++j)
            #pragma unroll
            for (int r = 0; r < 4; ++r) {
                int m = m0 + wm * 64 + i * 16 + lq * 4 + r;
                int n = n0 + wn * 64 + j * 16 + lr;
                size_t idx = (size_t)m * DM + n;
                out[idx] = acc[i][j][r] + (float)qnb[idx];
            }
}

// ---------------------------------------------------------------------------
// Flash attention v2: in-register online softmax, bf16 bias tile in LDS,
// pre-transposed V, VGPR prefetch of next K/Vt/bias tile.
// grid (32 q-blocks, 64 bh); 4 waves, each 16 q-rows; KV tile 64.
__global__ __launch_bounds__(256) void flash_attn(
    const bf16* __restrict__ Qb, const bf16* __restrict__ Kb,
    const bf16* __restrict__ Vtb, const bf16* __restrict__ bias,
    bf16* __restrict__ vec)
{
    __shared__ __align__(16) bf16 Ksm [64 * 72];    // [key][d]
    __shared__ __align__(16) bf16 Vtsm[64 * 72];    // [d][key]
    __shared__ __align__(16) bf16 Bsm_[64 * 72];    // bias [q within block][key]
    __shared__ __align__(16) bf16 Psm [4][16 * 72]; // per-wave P (wave-private)

    const int t = threadIdx.x, w = t >> 6, L = t & 63;
    const int lr = L & 15, lq = L >> 4;
    const int bh = blockIdx.y, b = bh >> 4, h = bh & 15;
    const int qblk = blockIdx.x * 64, q0 = qblk + w * 16;

    const bf16* Qh  = Qb  + (size_t)bh * SEQL * DHEAD;
    const bf16* Kh  = Kb  + (size_t)bh * SEQL * DHEAD;
    const bf16* Vth = Vtb + (size_t)bh * DHEAD * SEQL;

    // Q fragments (A-layout), resident
    bf16x8 qf[2];
    qf[0] = *(const bf16x8*)(Qh + (size_t)(q0 + lr) * DHEAD + lq * 8);
    qf[1] = *(const bf16x8*)(Qh + (size_t)(q0 + lr) * DHEAD + 32 + lq * 8);

    f32x4 o[4] = {};
    float mrow[4] = {-1e30f, -1e30f, -1e30f, -1e30f};
    float lrow[4] = {0.f, 0.f, 0.f, 0.f};

    const int sr = t >> 2, sc = (t & 3) * 16;       // staging lane -> (row, col)
    bf16x8 kreg[2], vreg[2], breg[2];
    #pragma unroll
    for (int u = 0; u < 2; ++u) {
        kreg[u] = *(const bf16x8*)(Kh  + (size_t)sr * DHEAD + sc + u * 8);
        vreg[u] = *(const bf16x8*)(Vth + (size_t)sr * SEQL + sc + u * 8);
        breg[u] = *(const bf16x8*)(bias + (size_t)(qblk + sr) * SEQL + sc + u * 8);
    }

    for (int kt = 0; kt < SEQL / 64; ++kt) {
        if (kt > 0) __syncthreads();                // prev iter readers done
        #pragma unroll
        for (int u = 0; u < 2; ++u) {
            *(bf16x8*)(Ksm  + sr * 72 + sc + u * 8) = kreg[u];
            *(bf16x8*)(Vtsm + sr * 72 + sc + u * 8) = vreg[u];
            *(bf16x8*)(Bsm_ + sr * 72 + sc + u * 8) = breg[u];
        }
        if (kt < SEQL / 64 - 1) {                   // prefetch next tile
            const int kb2 = (kt + 1) * 64;
            #pragma unroll
            for (int u = 0; u < 2; ++u) {
                kreg[u] = *(const bf16x8*)(Kh  + (size_t)(kb2 + sr) * DHEAD + sc + u * 8);
                vreg[u] = *(const bf16x8*)(Vth + (size_t)sr * SEQL + kb2 + sc + u * 8);
                breg[u] = *(const bf16x8*)(bias + (size_t)(qblk + sr) * SEQL + kb2 + sc + u * 8);
            }
        }
        __syncthreads();

        // S = Q K^T (16 x 64 per wave)
        f32x4 s[4] = {};
        #pragma unroll
        for (int ks = 0; ks < 2; ++ks) {
            bf16x8 a = qf[ks];
            #pragma unroll
            for (int jj = 0; jj < 4; ++jj) {
                bf16x8 bfr = *(const bf16x8*)(Ksm + (jj * 16 + lr) * 72 + ks * 32 + lq * 8);
                s[jj] = MFMA16(a, bfr, s[jj], 0, 0, 0);
            }
        }

        // in-register online softmax (row stats shared across 16-lane group)
        float alpha_r[4];
        #pragma unroll
        for (int r = 0; r < 4; ++r) {
            const int row = lq * 4 + r;
            float v[4];
            #pragma unroll
            for (int jj = 0; jj < 4; ++jj)
                v[jj] = s[jj][r] * SCL + (float)Bsm_[(w * 16 + row) * 72 + jj * 16 + lr];
            float mx = fmaxf(fmaxf(v[0], v[1]), fmaxf(v[2], v[3]));
            mx = fmaxf(mx, __shfl_xor(mx, 1));
            mx = fmaxf(mx, __shfl_xor(mx, 2));
            mx = fmaxf(mx, __shfl_xor(mx, 4));
            mx = fmaxf(mx, __shfl_xor(mx, 8));
            const float mo = mrow[r], mn = fmaxf(mo, mx);
            const float al = __expf(mo - mn);
            float ls = 0.0f;
            #pragma unroll
            for (int jj = 0; jj < 4; ++jj) {
                float p = __expf(v[jj] - mn);
                ls += p;
                Psm[w][row * 72 + jj * 16 + lr] = (bf16)p;
            }
            ls += __shfl_xor(ls, 1);
            ls += __shfl_xor(ls, 2);
            ls += __shfl_xor(ls, 4);
            ls += __shfl_xor(ls, 8);
            mrow[r] = mn;
            lrow[r] = lrow[r] * al + ls;
            alpha_r[r] = al;
        }

        // rescale O, then O += P V  (Psm is wave-private: no barrier needed)
        #pragma unroll
        for (int jj = 0; jj < 4; ++jj)
            #pragma unroll
            for (int r = 0; r < 4; ++r) o[jj][r] *= alpha_r[r];
        #pragma unroll
        for (int ks = 0; ks < 2; ++ks) {
            bf16x8 ap = *(const bf16x8*)(&Psm[w][lr * 72 + ks * 32 + lq * 8]);
            #pragma unroll
            for (int jj = 0; jj < 4; ++jj) {
                bf16x8 bv = *(const bf16x8*)(Vtsm + (jj * 16 + lr) * 72 + ks * 32 + lq * 8);
                o[jj] = MFMA16(ap, bv, o[jj], 0, 0, 0);
            }
        }
    }

    // epilogue: vec in (b, s, h*64+d)
    #pragma unroll
    for (int jj = 0; jj < 4; ++jj)
        #pragma unroll
        for (int r = 0; r < 4; ++r) {
            int row = lq * 4 + r;
            int srow = q0 + row;
            int d = jj * 16 + lr;
            vec[((size_t)b * SEQL + srow) * DM + h * DHEAD + d] = (bf16)(o[jj][r] / lrow[r]);
        }
}

// ---------------------------------------------------------------------------
extern "C" void kernel_launch(void* const* d_in, const int* in_sizes, int n_in,
                              void* d_out, int out_size, void* d_ws, size_t ws_size,
                              hipStream_t stream)
{
    const float* qin   = (const float*)d_in[0];
    const void*  mask  = d_in[1];
    const float* Wq    = (const float*)d_in[2];
    const float* Wk    = (const float*)d_in[3];
    const float* Wv    = (const float*)d_in[4];
    const float* Wo    = (const float*)d_in[5];
    const float* gamma = (const float*)d_in[6];
    const float* beta  = (const float*)d_in[7];
    float* out = (float*)d_out;

    char* w = (char*)d_ws;
    int*  flag = (int*)w;
    bf16* qnb  = (bf16*)(w + 256);                 // 8192x1024 bf16  (16 MB)
    bf16* Wt   = qnb + (size_t)8192 * 1024;        // 4x 1024x1024 bf16 (8 MB)
    bf16* Qb   = Wt + (size_t)4 * 1024 * 1024;     // (b,h,s,d)  (16 MB)
    bf16* Kb   = Qb + (size_t)8192 * 1024;         // (b,h,s,d)  (16 MB)
    bf16* Vtb  = Kb + (size_t)8192 * 1024;         // (b,h,d,s)  (16 MB)
    bf16* vec  = Vtb + (size_t)8192 * 1024;        // (b,s,h*d)  (16 MB)
    bf16* bias = vec + (size_t)8192 * 1024;        // 2048x2048 bf16 (8 MB)

    detect_mask<<<1, 256, 0, stream>>>((const unsigned int*)mask, flag);
    prep_bias<<<2048, 256, 0, stream>>>(mask, flag, bias);
    ln_kernel<<<8192, 256, 0, stream>>>(qin, gamma, beta, qnb);
    cvt_w<<<dim3(32, 32, 4), dim3(32, 8), 0, stream>>>(Wq, Wk, Wv, Wo, Wt);
    qkv128<<<dim3(64, 8, 3), 256, 0, stream>>>(qnb, Wt, Qb, Kb, Vtb);
    flash_attn<<<dim3(32, 64), 256, 0, stream>>>(Qb, Kb, Vtb, bias, vec);
    out128<<<dim3(64, 8), 256, 0, stream>>>(vec, Wt + (size_t)3 * 1024 * 1024, qnb, out);
}